// Round 1
// baseline (1286.017 us; speedup 1.0000x reference)
//
#include <hip/hip_runtime.h>
#include <hip/hip_bf16.h>

#define N_NODES 100000
#define N_EDGES 3200000
#define D_FEAT  256
#define UNITS   256

// ---------------- GEMM: h = X @ W  (fp32, 64x64 tile, BK=16) ----------------
__global__ __launch_bounds__(256) void gemm_xw(const float* __restrict__ X,
                                               const float* __restrict__ W,
                                               float* __restrict__ h) {
    __shared__ float As[16][64];   // As[k][row]
    __shared__ float Bs[16][64];   // Bs[k][col]
    const int t  = threadIdx.x;
    const int tx = t & 15, ty = t >> 4;
    const int rowBase = blockIdx.y * 64;
    const int colBase = blockIdx.x * 64;

    float acc[4][4] = {};

    // staging indices
    const int ar = t >> 2;          // 0..63 tile row
    const int ak = (t & 3) * 4;     // k quad 0,4,8,12
    const int bk = t >> 4;          // 0..15 k
    const int bc = (t & 15) * 4;    // col quad

    for (int k0 = 0; k0 < D_FEAT; k0 += 16) {
        float4 a4 = make_float4(0.f, 0.f, 0.f, 0.f);
        const int grow = rowBase + ar;
        if (grow < N_NODES)
            a4 = *(const float4*)(X + (size_t)grow * D_FEAT + k0 + ak);
        As[ak + 0][ar] = a4.x; As[ak + 1][ar] = a4.y;
        As[ak + 2][ar] = a4.z; As[ak + 3][ar] = a4.w;

        float4 b4 = *(const float4*)(W + (size_t)(k0 + bk) * UNITS + colBase + bc);
        *(float4*)&Bs[bk][bc] = b4;
        __syncthreads();

        #pragma unroll
        for (int k = 0; k < 16; ++k) {
            float4 av = *(float4*)&As[k][ty * 4];
            float4 bv = *(float4*)&Bs[k][tx * 4];
            float a[4] = {av.x, av.y, av.z, av.w};
            float b[4] = {bv.x, bv.y, bv.z, bv.w};
            #pragma unroll
            for (int i = 0; i < 4; ++i)
                #pragma unroll
                for (int j = 0; j < 4; ++j)
                    acc[i][j] += a[i] * b[j];
        }
        __syncthreads();
    }

    #pragma unroll
    for (int i = 0; i < 4; ++i) {
        const int r = rowBase + ty * 4 + i;
        if (r < N_NODES) {
            float4 v = make_float4(acc[i][0], acc[i][1], acc[i][2], acc[i][3]);
            *(float4*)(h + (size_t)r * UNITS + colBase + tx * 4) = v;
        }
    }
}

// ---------------- CSR build: count / scan / scatter ----------------
__global__ __launch_bounds__(256) void count_edges(const int* __restrict__ erow,
                                                   int* __restrict__ counts) {
    const int e = blockIdx.x * 256 + threadIdx.x;   // grid sized exactly
    atomicAdd(&counts[erow[e]], 1);
}

__global__ __launch_bounds__(1024) void scan_kernel(const int* __restrict__ counts,
                                                    int* __restrict__ offs,
                                                    int* __restrict__ cursor) {
    __shared__ int p[1024];
    const int t = threadIdx.x;
    const int n = N_NODES;
    const int chunk = (n + 1023) / 1024;            // 98
    const int start = t * chunk;
    const int end   = min(start + chunk, n);

    int s = 0;
    for (int i = start; i < end; ++i) s += counts[i];
    p[t] = s;
    __syncthreads();

    // Hillis-Steele inclusive scan
    for (int d = 1; d < 1024; d <<= 1) {
        int v = (t >= d) ? p[t - d] : 0;
        __syncthreads();
        p[t] += v;
        __syncthreads();
    }

    int run = p[t] - s;                              // exclusive prefix
    for (int i = start; i < end; ++i) {
        offs[i]   = run;
        cursor[i] = run;
        run += counts[i];
    }
    if (t == 1023) offs[n] = p[1023];
}

__global__ __launch_bounds__(256) void scatter_edges(const int* __restrict__ erow,
                                                     const int* __restrict__ ecol,
                                                     const float* __restrict__ eval,
                                                     int* __restrict__ cursor,
                                                     int* __restrict__ col_s,
                                                     float* __restrict__ val_s) {
    const int e = blockIdx.x * 256 + threadIdx.x;
    const int r = erow[e];
    const int pos = atomicAdd(&cursor[r], 1);
    col_s[pos] = ecol[e];
    val_s[pos] = eval[e];
}

// ---------------- row-SpMM + bias + ReLU ----------------
__global__ __launch_bounds__(256) void spmm_rows(const int* __restrict__ offs,
                                                 const int* __restrict__ col_s,
                                                 const float* __restrict__ val_s,
                                                 const float* __restrict__ h,
                                                 const float* __restrict__ bias,
                                                 float* __restrict__ out) {
    const int r = blockIdx.x;
    const int t = threadIdx.x;
    __shared__ int   lc[256];
    __shared__ float lv[256];

    int s = offs[r];
    const int e = offs[r + 1];
    float acc = 0.f;

    while (s < e) {
        const int cnt = min(256, e - s);
        if (t < cnt) {
            lc[t] = col_s[s + t];
            lv[t] = val_s[s + t];
        }
        __syncthreads();
        #pragma unroll 4
        for (int j = 0; j < cnt; ++j) {
            acc += lv[j] * h[(size_t)lc[j] * UNITS + t];
        }
        __syncthreads();
        s += cnt;
    }

    float v = acc + bias[t];
    out[(size_t)r * UNITS + t] = v > 0.f ? v : 0.f;
}

// ---------------- launch ----------------
extern "C" void kernel_launch(void* const* d_in, const int* in_sizes, int n_in,
                              void* d_out, int out_size, void* d_ws, size_t ws_size,
                              hipStream_t stream) {
    const float* X    = (const float*)d_in[0];
    const int*   erow = (const int*)  d_in[1];
    const int*   ecol = (const int*)  d_in[2];
    const float* evalv= (const float*)d_in[3];
    const float* W    = (const float*)d_in[4];
    const float* bias = (const float*)d_in[5];
    float* out = (float*)d_out;

    char* ws = (char*)d_ws;
    size_t off = 0;
    float* h     = (float*)(ws + off); off += (size_t)N_NODES * UNITS * sizeof(float);
    int*   col_s = (int*)  (ws + off); off += (size_t)N_EDGES * sizeof(int);
    float* val_s = (float*)(ws + off); off += (size_t)N_EDGES * sizeof(float);
    int*   counts= (int*)  (ws + off); off += (size_t)N_NODES * sizeof(int);
    int*   offs  = (int*)  (ws + off); off += (size_t)(N_NODES + 1) * sizeof(int);
    int*   cursor= (int*)  (ws + off); off += (size_t)N_NODES * sizeof(int);

    hipMemsetAsync(counts, 0, (size_t)N_NODES * sizeof(int), stream);

    gemm_xw<<<dim3(UNITS / 64, (N_NODES + 63) / 64), 256, 0, stream>>>(X, W, h);
    count_edges<<<N_EDGES / 256, 256, 0, stream>>>(erow, counts);
    scan_kernel<<<1, 1024, 0, stream>>>(counts, offs, cursor);
    scatter_edges<<<N_EDGES / 256, 256, 0, stream>>>(erow, ecol, evalv, cursor, col_s, val_s);
    spmm_rows<<<N_NODES, 256, 0, stream>>>(offs, col_s, val_s, h, bias, out);
}

// Round 2
// 1037.239 us; speedup vs baseline: 1.2398x; 1.2398x over previous
//
#include <hip/hip_runtime.h>
#include <hip/hip_bf16.h>

#define N_NODES 100000
#define N_EDGES 3200000
#define D_FEAT  256
#define UNITS   256
#define PADM    100096   // 782 * 128, padded row count for GEMM tiles

using frag_ab = __attribute__((ext_vector_type(8))) short;   // 8 bf16 = 4 VGPRs
using frag_cd = __attribute__((ext_vector_type(4))) float;   // 4 fp32 acc

__device__ __forceinline__ float bf2f(unsigned short u) {
    union { unsigned int i; float f; } c; c.i = ((unsigned int)u) << 16; return c.f;
}
__device__ __forceinline__ unsigned short f2bf(float f) {
    union { float f; unsigned int i; } c; c.f = f;
    unsigned int r = c.i + 0x7FFF + ((c.i >> 16) & 1);   // round-nearest-even
    return (unsigned short)(r >> 16);
}

// ---------------- X fp32 -> bf16 (padded to PADM rows) ----------------
__global__ __launch_bounds__(256) void convert_x(const float* __restrict__ X,
                                                 unsigned short* __restrict__ Xb) {
    const size_t e = ((size_t)blockIdx.x * 256 + threadIdx.x) * 4;
    const int row = (int)(e >> 8);
    ushort4 o;
    if (row < N_NODES) {
        const float4 v = *(const float4*)(X + e);
        o.x = f2bf(v.x); o.y = f2bf(v.y); o.z = f2bf(v.z); o.w = f2bf(v.w);
    } else {
        o = make_ushort4(0, 0, 0, 0);
    }
    *(ushort4*)(Xb + e) = o;
}

// ---------------- W fp32 [k][n] -> bf16 W^T [n][k] ----------------
__global__ __launch_bounds__(256) void convert_wt(const float* __restrict__ W,
                                                  unsigned short* __restrict__ Wt) {
    const int n = blockIdx.x, k = threadIdx.x;
    Wt[n * 256 + k] = f2bf(W[k * 256 + n]);
}

// ---------------- GEMM: h = X @ W, bf16 MFMA, 128x128 tile, BK=32 ----------------
__global__ __launch_bounds__(256) void gemm_mfma(const unsigned short* __restrict__ Xb,
                                                 const unsigned short* __restrict__ Wt,
                                                 unsigned short* __restrict__ hb) {
    __shared__ unsigned short As[128 * 32];   // [m][k], 8 KB
    __shared__ unsigned short Bs[128 * 32];   // [n][k], 8 KB
    const int t    = threadIdx.x;
    const int lane = t & 63;
    const int wave = t >> 6;
    const int wm   = (wave >> 1) * 64;        // wave sub-tile row
    const int wn   = (wave & 1) * 64;         // wave sub-tile col
    const int rowBase = blockIdx.y * 128;
    const int colBase = blockIdx.x * 128;
    const int lr = lane & 15, lq = lane >> 4;

    frag_cd acc[4][4];
    #pragma unroll
    for (int i = 0; i < 4; ++i)
        #pragma unroll
        for (int j = 0; j < 4; ++j)
            acc[i][j] = (frag_cd){0.f, 0.f, 0.f, 0.f};

    for (int k0 = 0; k0 < D_FEAT; k0 += 32) {
        // stage A,B tiles: 512 chunks of 16B each; chunk c -> row c>>2, koff (c&3)*8
        #pragma unroll
        for (int cc = 0; cc < 2; ++cc) {
            const int c = t + cc * 256;
            const int r = c >> 2, ko = (c & 3) * 8;
            *(uint4*)(As + c * 8) =
                *(const uint4*)(Xb + (size_t)(rowBase + r) * 256 + k0 + ko);
            *(uint4*)(Bs + c * 8) =
                *(const uint4*)(Wt + (size_t)(colBase + r) * 256 + k0 + ko);
        }
        __syncthreads();

        frag_ab a[4], b[4];
        #pragma unroll
        for (int i = 0; i < 4; ++i)
            a[i] = *(const frag_ab*)(As + (wm + i * 16 + lr) * 32 + lq * 8);
        #pragma unroll
        for (int j = 0; j < 4; ++j)
            b[j] = *(const frag_ab*)(Bs + (wn + j * 16 + lr) * 32 + lq * 8);

        #pragma unroll
        for (int i = 0; i < 4; ++i)
            #pragma unroll
            for (int j = 0; j < 4; ++j)
                acc[i][j] = __builtin_amdgcn_mfma_f32_16x16x32_bf16(
                    a[i], b[j], acc[i][j], 0, 0, 0);
        __syncthreads();
    }

    // epilogue: C/D layout col=lane&15, row=(lane>>4)*4+reg
    #pragma unroll
    for (int i = 0; i < 4; ++i) {
        #pragma unroll
        for (int rr = 0; rr < 4; ++rr) {
            const int row = rowBase + wm + i * 16 + lq * 4 + rr;
            if (row < N_NODES) {
                #pragma unroll
                for (int j = 0; j < 4; ++j) {
                    hb[(size_t)row * 256 + colBase + wn + j * 16 + lr] =
                        f2bf(acc[i][j][rr]);
                }
            }
        }
    }
}

// ---------------- CSR build ----------------
__global__ __launch_bounds__(256) void count_edges(const int* __restrict__ erow,
                                                   int* __restrict__ counts) {
    const int e = blockIdx.x * 256 + threadIdx.x;
    atomicAdd(&counts[erow[e]], 1);
}

__global__ __launch_bounds__(1024) void scan_kernel(const int* __restrict__ counts,
                                                    int* __restrict__ offs,
                                                    int* __restrict__ cursor) {
    __shared__ int p[1024];
    const int t = threadIdx.x;
    const int n = N_NODES;
    const int chunk = (n + 1023) / 1024;
    const int start = t * chunk;
    const int end   = min(start + chunk, n);

    int s = 0;
    for (int i = start; i < end; ++i) s += counts[i];
    p[t] = s;
    __syncthreads();
    for (int d = 1; d < 1024; d <<= 1) {
        int v = (t >= d) ? p[t - d] : 0;
        __syncthreads();
        p[t] += v;
        __syncthreads();
    }
    int run = p[t] - s;
    for (int i = start; i < end; ++i) {
        offs[i]   = run;
        cursor[i] = run;
        run += counts[i];
    }
    if (t == 1023) offs[n] = p[1023];
}

__global__ __launch_bounds__(256) void scatter_edges(const int* __restrict__ erow,
                                                     const int* __restrict__ ecol,
                                                     const float* __restrict__ eval,
                                                     int* __restrict__ cursor,
                                                     uint2* __restrict__ packed) {
    const int e = blockIdx.x * 256 + threadIdx.x;
    const int r = erow[e];
    const int pos = atomicAdd(&cursor[r], 1);
    packed[pos] = make_uint2((unsigned)ecol[e], __float_as_uint(eval[e]));
}

// ---------------- row-SpMM + bias + ReLU (1 wave/row, 4 feats/lane) ----------------
__global__ __launch_bounds__(64) void spmm_rows(const int* __restrict__ offs,
                                                const uint2* __restrict__ packed,
                                                const unsigned short* __restrict__ hb,
                                                const float* __restrict__ bias,
                                                float* __restrict__ out) {
    const int r = blockIdx.x;
    const int lane = threadIdx.x;
    __shared__ uint2 le[64];
    int s = offs[r];
    const int e = offs[r + 1];
    float a0 = 0.f, a1 = 0.f, a2 = 0.f, a3 = 0.f;

    while (s < e) {
        const int cnt = min(64, e - s);
        if (lane < cnt) le[lane] = packed[s + lane];
        __syncthreads();
        #pragma unroll 4
        for (int j = 0; j < cnt; ++j) {
            const uint2 cv = le[j];
            const float v = __uint_as_float(cv.y);
            const ushort4 hv = *(const ushort4*)(hb + (size_t)cv.x * 256 + lane * 4);
            a0 += v * bf2f(hv.x);
            a1 += v * bf2f(hv.y);
            a2 += v * bf2f(hv.z);
            a3 += v * bf2f(hv.w);
        }
        __syncthreads();
        s += cnt;
    }

    const float4 b4 = *(const float4*)(bias + lane * 4);
    float4 o;
    o.x = fmaxf(a0 + b4.x, 0.f);
    o.y = fmaxf(a1 + b4.y, 0.f);
    o.z = fmaxf(a2 + b4.z, 0.f);
    o.w = fmaxf(a3 + b4.w, 0.f);
    *(float4*)(out + (size_t)r * 256 + lane * 4) = o;
}

// ---------------- launch ----------------
extern "C" void kernel_launch(void* const* d_in, const int* in_sizes, int n_in,
                              void* d_out, int out_size, void* d_ws, size_t ws_size,
                              hipStream_t stream) {
    const float* X    = (const float*)d_in[0];
    const int*   erow = (const int*)  d_in[1];
    const int*   ecol = (const int*)  d_in[2];
    const float* evalv= (const float*)d_in[3];
    const float* W    = (const float*)d_in[4];
    const float* bias = (const float*)d_in[5];
    float* out = (float*)d_out;

    char* ws = (char*)d_ws;
    size_t off = 0;
    unsigned short* Xb  = (unsigned short*)(ws + off); off += (size_t)PADM * D_FEAT * 2;
    unsigned short* Wt  = (unsigned short*)(ws + off); off += (size_t)D_FEAT * UNITS * 2;
    unsigned short* hb  = (unsigned short*)(ws + off); off += (size_t)N_NODES * UNITS * 2;
    uint2*          packed = (uint2*)     (ws + off); off += (size_t)N_EDGES * 8;
    int*            counts = (int*)       (ws + off); off += (size_t)N_NODES * 4;
    int*            cursor = (int*)       (ws + off); off += (size_t)N_NODES * 4;
    int*            offs   = (int*)       (ws + off); off += ((size_t)N_NODES + 4) * 4;

    hipMemsetAsync(counts, 0, (size_t)N_NODES * sizeof(int), stream);

    convert_x<<<PADM / 4, 256, 0, stream>>>(X, Xb);
    convert_wt<<<UNITS, 256, 0, stream>>>(W, Wt);
    gemm_mfma<<<dim3(UNITS / 128, PADM / 128), 256, 0, stream>>>(Xb, Wt, hb);
    count_edges<<<N_EDGES / 256, 256, 0, stream>>>(erow, counts);
    scan_kernel<<<1, 1024, 0, stream>>>(counts, offs, cursor);
    scatter_edges<<<N_EDGES / 256, 256, 0, stream>>>(erow, ecol, evalv, cursor, packed);
    spmm_rows<<<N_NODES, 64, 0, stream>>>(offs, packed, hb, bias, out);
}

// Round 4
// 549.988 us; speedup vs baseline: 2.3383x; 1.8859x over previous
//
#include <hip/hip_runtime.h>
#include <hip/hip_bf16.h>

#define N_NODES 100000
#define N_EDGES 3200000
#define D_FEAT  256
#define UNITS   256

#define BROWS   128                      // rows per bucket
#define NB      782                      // ceil(100000/128)
#define NCHUNK  256                      // blocks for hist/scatter
#define EPB     (N_EDGES / NCHUNK)       // 12500 edges per block (exact)
#define MAXB    6144                     // bucket capacity (mean 4096, sigma 64)

using frag_ab = __attribute__((ext_vector_type(8))) short;   // 8 bf16 = 4 VGPRs
using frag_cd = __attribute__((ext_vector_type(4))) float;   // 4 fp32 acc

__device__ __forceinline__ float bf2f(unsigned short u) {
    union { unsigned int i; float f; } c; c.i = ((unsigned int)u) << 16; return c.f;
}
__device__ __forceinline__ unsigned short f2bf(float f) {
    union { float f; unsigned int i; } c; c.f = f;
    unsigned int r = c.i + 0x7FFF + ((c.i >> 16) & 1);   // round-nearest-even
    return (unsigned short)(r >> 16);
}

// ---------------- W fp32 [k][n] -> bf16 W^T [n][k] ----------------
__global__ __launch_bounds__(256) void convert_wt(const float* __restrict__ W,
                                                  unsigned short* __restrict__ Wt) {
    const int n = blockIdx.x, k = threadIdx.x;
    Wt[n * 256 + k] = f2bf(W[k * 256 + n]);
}

// ---------------- GEMM: h = X @ W, fused fp32->bf16 convert on A-load ----------------
__global__ __launch_bounds__(256) void gemm_mfma(const float* __restrict__ X,
                                                 const unsigned short* __restrict__ Wt,
                                                 unsigned short* __restrict__ hb) {
    __shared__ unsigned short As[128 * 32];   // [m][k] bf16, 8 KB
    __shared__ unsigned short Bs[128 * 32];   // [n][k] bf16, 8 KB
    const int t    = threadIdx.x;
    const int lane = t & 63;
    const int wave = t >> 6;
    const int wm   = (wave >> 1) * 64;
    const int wn   = (wave & 1) * 64;
    const int rowBase = blockIdx.y * 128;
    const int colBase = blockIdx.x * 128;
    const int lr = lane & 15, lq = lane >> 4;

    frag_cd acc[4][4];
    #pragma unroll
    for (int i = 0; i < 4; ++i)
        #pragma unroll
        for (int j = 0; j < 4; ++j)
            acc[i][j] = (frag_cd){0.f, 0.f, 0.f, 0.f};

    for (int k0 = 0; k0 < D_FEAT; k0 += 32) {
        // A tile: 128 rows x 32 k of X (fp32), convert to bf16 in-flight.
        #pragma unroll
        for (int cc = 0; cc < 4; ++cc) {
            const int c = t + cc * 256;
            const int r = c >> 3, fo = (c & 7) * 4;
            const int grow = min(rowBase + r, N_NODES - 1);   // clamp; excess rows never stored
            const float4 xv = *(const float4*)(X + (size_t)grow * D_FEAT + k0 + fo);
            ushort4 o;
            o.x = f2bf(xv.x); o.y = f2bf(xv.y); o.z = f2bf(xv.z); o.w = f2bf(xv.w);
            *(ushort4*)(As + r * 32 + fo) = o;
        }
        // B tile: 128 n x 32 k bf16, 512 16B-chunks
        #pragma unroll
        for (int cc = 0; cc < 2; ++cc) {
            const int c = t + cc * 256;
            const int r = c >> 2, ko = (c & 3) * 8;
            *(uint4*)(Bs + c * 8) =
                *(const uint4*)(Wt + (size_t)(colBase + r) * 256 + k0 + ko);
        }
        __syncthreads();

        frag_ab a[4], b[4];
        #pragma unroll
        for (int i = 0; i < 4; ++i)
            a[i] = *(const frag_ab*)(As + (wm + i * 16 + lr) * 32 + lq * 8);
        #pragma unroll
        for (int j = 0; j < 4; ++j)
            b[j] = *(const frag_ab*)(Bs + (wn + j * 16 + lr) * 32 + lq * 8);

        #pragma unroll
        for (int i = 0; i < 4; ++i)
            #pragma unroll
            for (int j = 0; j < 4; ++j)
                acc[i][j] = __builtin_amdgcn_mfma_f32_16x16x32_bf16(
                    a[i], b[j], acc[i][j], 0, 0, 0);
        __syncthreads();
    }

    // epilogue: C/D layout col=lane&15, row=(lane>>4)*4+reg
    #pragma unroll
    for (int i = 0; i < 4; ++i) {
        #pragma unroll
        for (int rr = 0; rr < 4; ++rr) {
            const int row = rowBase + wm + i * 16 + lq * 4 + rr;
            if (row < N_NODES) {
                #pragma unroll
                for (int j = 0; j < 4; ++j) {
                    hb[(size_t)row * 256 + colBase + wn + j * 16 + lr] =
                        f2bf(acc[i][j][rr]);
                }
            }
        }
    }
}

// ---------------- K1: per-block bucket histogram (no global atomics) ----------------
__global__ __launch_bounds__(256) void hist_kernel(const int* __restrict__ erow,
                                                   int* __restrict__ hist_g) {
    __shared__ int h[NB];
    const int t = threadIdx.x;
    const int b = blockIdx.x;
    for (int i = t; i < NB; i += 256) h[i] = 0;
    __syncthreads();
    const int base_e = b * EPB;
    for (int i = t; i < EPB; i += 256)
        atomicAdd(&h[erow[base_e + i] >> 7], 1);
    __syncthreads();
    for (int i = t; i < NB; i += 256)
        hist_g[b * NB + i] = h[i];
}

// ---------------- K2a: per-bucket scan over blocks ----------------
__global__ __launch_bounds__(256) void scan_buckets(const int* __restrict__ hist_g,
                                                    int* __restrict__ cum,
                                                    int* __restrict__ total) {
    const int k = blockIdx.x, t = threadIdx.x;
    __shared__ int p[256];
    const int v = hist_g[t * NB + k];
    p[t] = v;
    __syncthreads();
    for (int d = 1; d < 256; d <<= 1) {
        const int u = (t >= d) ? p[t - d] : 0;
        __syncthreads();
        p[t] += u;
        __syncthreads();
    }
    cum[t * NB + k] = p[t] - v;            // exclusive prefix for (block t, bucket k)
    if (t == 255) total[k] = p[255];
}

// ---------------- K2b: scan bucket totals -> base offsets ----------------
__global__ __launch_bounds__(1024) void scan_base(const int* __restrict__ total,
                                                  int* __restrict__ base) {
    const int t = threadIdx.x;
    __shared__ int p[1024];
    const int v = (t < NB) ? total[t] : 0;
    p[t] = v;
    __syncthreads();
    for (int d = 1; d < 1024; d <<= 1) {
        const int u = (t >= d) ? p[t - d] : 0;
        __syncthreads();
        p[t] += u;
        __syncthreads();
    }
    if (t < NB) base[t] = p[t] - v;
    if (t == NB - 1) base[NB] = p[t];
}

// ---------------- K3: binned scatter, private ranges (no global atomics) ----------------
__global__ __launch_bounds__(256) void scatter_binned(const int* __restrict__ erow,
                                                      const int* __restrict__ ecol,
                                                      const float* __restrict__ eval,
                                                      const int* __restrict__ cum,
                                                      const int* __restrict__ base,
                                                      uint2* __restrict__ binned) {
    __shared__ int cur[NB];
    const int t = threadIdx.x;
    const int b = blockIdx.x;
    for (int i = t; i < NB; i += 256)
        cur[i] = base[i] + cum[b * NB + i];
    __syncthreads();
    const int base_e = b * EPB;
    for (int i = t; i < EPB; i += 256) {
        const int e = base_e + i;
        const int r = erow[e];
        const int c = ecol[e];
        const float v = eval[e];
        const int k = r >> 7, rl = r & 127;
        const int pos = atomicAdd(&cur[k], 1);          // LDS atomic
        binned[pos] = make_uint2(((unsigned)rl << 17) | (unsigned)c,
                                 __float_as_uint(v));
    }
}

// ---------------- K4: per-bucket local row-sort + offs ----------------
__global__ __launch_bounds__(256) void sort_local(const uint2* __restrict__ binned,
                                                  const int* __restrict__ base,
                                                  const int* __restrict__ total,
                                                  uint2* __restrict__ sorted,
                                                  int* __restrict__ offs) {
    __shared__ uint2 buf[MAXB];     // 48 KB
    __shared__ int lh[BROWS], loff[BROWS], lcur[BROWS];
    const int k = blockIdx.x, t = threadIdx.x;
    const int s = base[k];
    const int cnt = min(total[k], MAXB);

    if (t < BROWS) lh[t] = 0;
    __syncthreads();
    for (int i = t; i < cnt; i += 256)
        atomicAdd(&lh[binned[s + i].x >> 17], 1);
    __syncthreads();
    if (t < BROWS) loff[t] = lh[t];
    __syncthreads();
    for (int d = 1; d < BROWS; d <<= 1) {
        const int u = (t >= d && t < BROWS) ? loff[t - d] : 0;
        __syncthreads();
        if (t < BROWS) loff[t] += u;
        __syncthreads();
    }
    if (t < BROWS) lcur[t] = loff[t] - lh[t];          // exclusive
    __syncthreads();
    for (int i = t; i < cnt; i += 256) {
        const uint2 eo = binned[s + i];
        const int rl = eo.x >> 17;
        const int p = atomicAdd(&lcur[rl], 1);          // LDS atomic
        buf[p] = make_uint2(eo.x & 0x1FFFF, eo.y);
    }
    __syncthreads();
    for (int i = t; i < cnt; i += 256)
        sorted[s + i] = buf[i];
    const int rowBase = k * BROWS;
    if (t < BROWS && rowBase + t < N_NODES)
        offs[rowBase + t] = s + (loff[t] - lh[t]);
    if (t == 0 && k == NB - 1)
        offs[N_NODES] = N_EDGES;
}

// ---------------- K5: row-SpMM + bias + ReLU (1 wave/row, 4 feats/lane) ----------------
__global__ __launch_bounds__(64) void spmm_rows(const int* __restrict__ offs,
                                                const uint2* __restrict__ sorted,
                                                const unsigned short* __restrict__ hb,
                                                const float* __restrict__ bias,
                                                float* __restrict__ out) {
    const int r = blockIdx.x;
    const int lane = threadIdx.x;
    __shared__ uint2 le[64];
    int s = offs[r];
    const int e = offs[r + 1];
    float a0 = 0.f, a1 = 0.f, a2 = 0.f, a3 = 0.f;

    while (s < e) {
        const int cnt = min(64, e - s);
        if (lane < cnt) {
            uint2 v = sorted[s + lane];
            v.x &= 0x1FFFF;                 // defensive: col always < N_NODES
            le[lane] = v;
        }
        __syncthreads();
        #pragma unroll 4
        for (int j = 0; j < cnt; ++j) {
            const uint2 cv = le[j];
            const float v = __uint_as_float(cv.y);
            const ushort4 hv = *(const ushort4*)(hb + (size_t)cv.x * 256 + lane * 4);
            a0 += v * bf2f(hv.x);
            a1 += v * bf2f(hv.y);
            a2 += v * bf2f(hv.z);
            a3 += v * bf2f(hv.w);
        }
        __syncthreads();
        s += cnt;
    }

    const float4 b4 = *(const float4*)(bias + lane * 4);
    float4 o;
    o.x = fmaxf(a0 + b4.x, 0.f);
    o.y = fmaxf(a1 + b4.y, 0.f);
    o.z = fmaxf(a2 + b4.z, 0.f);
    o.w = fmaxf(a3 + b4.w, 0.f);
    *(float4*)(out + (size_t)r * 256 + lane * 4) = o;
}

// ---------------- launch ----------------
extern "C" void kernel_launch(void* const* d_in, const int* in_sizes, int n_in,
                              void* d_out, int out_size, void* d_ws, size_t ws_size,
                              hipStream_t stream) {
    const float* X    = (const float*)d_in[0];
    const int*   erow = (const int*)  d_in[1];
    const int*   ecol = (const int*)  d_in[2];
    const float* evalv= (const float*)d_in[3];
    const float* W    = (const float*)d_in[4];
    const float* bias = (const float*)d_in[5];
    float* out = (float*)d_out;

    char* ws = (char*)d_ws;
    size_t off = 0;
    auto alloc = [&](size_t bytes) {
        void* p = ws + off;
        off += (bytes + 255) & ~(size_t)255;
        return p;
    };
    unsigned short* Wt     = (unsigned short*)alloc((size_t)D_FEAT * UNITS * 2);
    unsigned short* hb     = (unsigned short*)alloc((size_t)N_NODES * UNITS * 2);
    uint2*          binned = (uint2*)         alloc((size_t)N_EDGES * 8);
    uint2*          sorted = (uint2*)         alloc((size_t)N_EDGES * 8);
    int*            hist_g = (int*)           alloc((size_t)NCHUNK * NB * 4);
    int*            cum    = (int*)           alloc((size_t)NCHUNK * NB * 4);
    int*            total  = (int*)           alloc((size_t)NB * 4);
    int*            basep  = (int*)           alloc((size_t)(NB + 1) * 4);
    int*            offs   = (int*)           alloc((size_t)(N_NODES + 1) * 4);

    convert_wt<<<UNITS, 256, 0, stream>>>(W, Wt);
    gemm_mfma<<<dim3(UNITS / 128, (N_NODES + 127) / 128), 256, 0, stream>>>(X, Wt, hb);
    hist_kernel<<<NCHUNK, 256, 0, stream>>>(erow, hist_g);
    scan_buckets<<<NB, 256, 0, stream>>>(hist_g, cum, total);
    scan_base<<<1, 1024, 0, stream>>>(total, basep);
    scatter_binned<<<NCHUNK, 256, 0, stream>>>(erow, ecol, evalv, cum, basep, binned);
    sort_local<<<NB, 256, 0, stream>>>(binned, basep, total, sorted, offs);
    spmm_rows<<<N_NODES, 64, 0, stream>>>(offs, sorted, hb, bias, out);
}